// Round 1
// baseline (1908.400 us; speedup 1.0000x reference)
//
#include <hip/hip_runtime.h>
#include <stdint.h>

// DualPrimalEdgePooling on MI355X.
// Pipeline: radix-select threshold -> union-find CC (min-id roots) ->
// root-rank scan -> counting-sort segmented mean (primal) ->
// pair bitmap + popcount-prefix ranking (dual) -> dual mean.

#define N_NODES 200000
#define N_EDGES 600000
#define FDIM 128
#define R_KEEP 300000u   // E - num_pool = NUM_KEEP; ascending-rank boundary

#define SC_B 0
#define SC_CLT 1
#define SC_T 2
#define SC_NEEDEQ 3
#define SC_TIECNT 4
#define SC_C 5
#define SC_W 6
#define SC_U 7
#define SC_VCNT 8
#define TIECAP 4096
#define SEG_CH 128

__device__ __forceinline__ uint32_t f2ou(float f){
  uint32_t b = __float_as_uint(f);
  return (b & 0x80000000u) ? ~b : (b | 0x80000000u);
}

// ---- union-find (agent-scope loads for cross-XCD coherence) ----
__device__ __forceinline__ int ld_par(int* p, int i){
  return __hip_atomic_load(&p[i], __ATOMIC_RELAXED, __HIP_MEMORY_SCOPE_AGENT);
}
__device__ __forceinline__ void st_par(int* p, int i, int v){
  __hip_atomic_store(&p[i], v, __ATOMIC_RELAXED, __HIP_MEMORY_SCOPE_AGENT);
}
__device__ int find_root(int* p, int x){
  int px = ld_par(p, x);
  while(px != x){
    int gp = ld_par(p, px);
    if(gp != px) st_par(p, x, gp);   // path halving
    x = px; px = gp;
  }
  return x;
}
__device__ void unite(int* p, int a, int b){
  int ra = find_root(p, a), rb = find_root(p, b);
  while(ra != rb){
    if(ra > rb){ int t = ra; ra = rb; rb = t; }
    int old = atomicCAS(&p[rb], rb, ra);   // hook larger root under smaller
    if(old == rb) return;
    rb = find_root(p, old);
  }
}

// ---- selection ----
__global__ void k_hist1(const float* att, uint32_t* hist){
  int e = blockIdx.x*256 + threadIdx.x;
  if(e < N_EDGES) atomicAdd(&hist[f2ou(att[e]) >> 16], 1u);
}
__global__ void k_hist2(const float* att, uint32_t* hist2, const uint32_t* sc){
  int e = blockIdx.x*256 + threadIdx.x;
  if(e >= N_EDGES) return;
  uint32_t u = f2ou(att[e]);
  if((u >> 16) == sc[SC_B]) atomicAdd(&hist2[u & 0xFFFFu], 1u);
}
__global__ __launch_bounds__(1024) void k_select_scan(const uint32_t* hist, uint32_t* sc, int phase){
  __shared__ uint32_t sm[1024];
  int t = threadIdx.x;
  uint32_t target = (phase == 1) ? (R_KEEP + 1u) : (R_KEEP + 1u - sc[SC_CLT]);
  uint32_t base = (uint32_t)t * 64u;
  uint32_t loc = 0;
  for(int k = 0; k < 64; k++) loc += hist[base + k];
  sm[t] = loc; __syncthreads();
  for(int off = 1; off < 1024; off <<= 1){
    uint32_t y = (t >= off) ? sm[t - off] : 0u;
    __syncthreads(); sm[t] += y; __syncthreads();
  }
  uint32_t incl = sm[t];
  uint32_t excl = incl - loc;
  if(excl < target && target <= incl){
    uint32_t c = excl; uint32_t bin = 0;
    for(int k = 0; k < 64; k++){
      c += hist[base + k];
      if(c >= target){ bin = base + k; break; }
    }
    if(phase == 1){ sc[SC_B] = bin; sc[SC_CLT] = c - hist[bin]; }
    else {
      uint32_t cumLE = sc[SC_CLT] + c;
      sc[SC_T] = (sc[SC_B] << 16) | bin;
      sc[SC_NEEDEQ] = cumLE - R_KEEP;
    }
  }
}
__global__ void k_mask(const float* att, uint8_t* mask, uint32_t* sc, uint32_t* tieIdx){
  int e = blockIdx.x*256 + threadIdx.x;
  if(e >= N_EDGES) return;
  uint32_t T = sc[SC_T];
  uint32_t u = f2ou(att[e]);
  mask[e] = (u > T) ? 1 : 0;
  if(u == T){
    uint32_t p = atomicAdd(&sc[SC_TIECNT], 1u);
    if(p < TIECAP) tieIdx[p] = (uint32_t)e;
  }
}
__global__ __launch_bounds__(1024) void k_tiesel(uint8_t* mask, const uint32_t* sc, const uint32_t* tieIdx){
  uint32_t m = sc[SC_TIECNT]; if(m > TIECAP) m = TIECAP;
  uint32_t need = sc[SC_NEEDEQ];
  for(uint32_t i = threadIdx.x; i < m; i += 1024){
    uint32_t mine = tieIdx[i];
    uint32_t r = 0;
    for(uint32_t j = 0; j < m; j++) r += (tieIdx[j] < mine) ? 1u : 0u;
    mask[mine] = (r < need) ? 1 : 0;   // stable argsort: smallest indices pooled
  }
}

// ---- union-find kernels ----
__global__ void k_uf_init(int* parent){
  int i = blockIdx.x*256 + threadIdx.x;
  if(i < N_NODES) parent[i] = i;
}
__global__ void k_uf_union(const int* src, const int* dst, const uint8_t* mask, int* parent){
  int e = blockIdx.x*256 + threadIdx.x;
  if(e >= N_EDGES) return;
  if(!mask[e]) return;
  int a = src[e], b = dst[e];
  if(a == b) return;
  unite(parent, a, b);
}
__global__ void k_flatten(int* parent, int* labels, uint32_t* flags){
  int i = blockIdx.x*256 + threadIdx.x;
  if(i >= N_NODES) return;
  int r = find_root(parent, i);
  labels[i] = r;
  flags[i] = (r == i) ? 1u : 0u;
}

// ---- generic exclusive scan (2048 items/block). MODE 0: identity, static len. MODE 1: popc, len = sc[SC_W] ----
template<int MODE>
__global__ void k_scan_reduce(const uint32_t* in, uint32_t* bsums, const uint32_t* sc, uint32_t staticLen){
  uint32_t n = (MODE == 1) ? sc[SC_W] : staticLen;
  uint32_t base = blockIdx.x*2048u + threadIdx.x*8u;
  uint32_t s = 0;
  #pragma unroll
  for(int k = 0; k < 8; k++){
    uint32_t idx = base + k;
    if(idx < n){ uint32_t v = in[idx]; if(MODE == 1) v = __popc(v); s += v; }
  }
  __shared__ uint32_t sm[256];
  sm[threadIdx.x] = s; __syncthreads();
  for(int off = 128; off > 0; off >>= 1){
    if((int)threadIdx.x < off) sm[threadIdx.x] += sm[threadIdx.x + off];
    __syncthreads();
  }
  if(threadIdx.x == 0) bsums[blockIdx.x] = sm[0];
}
__global__ __launch_bounds__(1024) void k_scan_top(uint32_t* bsums, int nb, uint32_t* sc, int extras){
  __shared__ uint32_t sm[1024];
  int t = threadIdx.x;
  uint32_t xs[4]; uint32_t tsum = 0;
  #pragma unroll
  for(int k = 0; k < 4; k++){ int idx = t*4 + k; xs[k] = (idx < nb) ? bsums[idx] : 0u; tsum += xs[k]; }
  sm[t] = tsum; __syncthreads();
  for(int off = 1; off < 1024; off <<= 1){
    uint32_t y = (t >= off) ? sm[t - off] : 0u;
    __syncthreads(); sm[t] += y; __syncthreads();
  }
  uint32_t run = sm[t] - tsum;
  #pragma unroll
  for(int k = 0; k < 4; k++){ int idx = t*4 + k; if(idx < nb) bsums[idx] = run; run += xs[k]; }
  uint32_t total = sm[1023];
  if(t == 0){
    if(extras == 1){ sc[SC_C] = total; uint64_t cc = (uint64_t)total*(uint64_t)total; sc[SC_W] = (uint32_t)((cc + 31ull) >> 5); }
    else if(extras == 2){ sc[SC_U] = total; }
  }
}
template<int MODE>
__global__ void k_scan_apply(const uint32_t* in, const uint32_t* bsums, uint32_t* out, const uint32_t* sc, uint32_t staticLen){
  uint32_t n = (MODE == 1) ? sc[SC_W] : staticLen;
  uint32_t base = blockIdx.x*2048u + threadIdx.x*8u;
  uint32_t xs[8]; uint32_t tsum = 0;
  #pragma unroll
  for(int k = 0; k < 8; k++){
    uint32_t idx = base + k; uint32_t v = 0;
    if(idx < n){ v = in[idx]; if(MODE == 1) v = __popc(v); }
    xs[k] = v; tsum += v;
  }
  __shared__ uint32_t sm[256];
  sm[threadIdx.x] = tsum; __syncthreads();
  for(int off = 1; off < 256; off <<= 1){
    uint32_t y = ((int)threadIdx.x >= off) ? sm[threadIdx.x - off] : 0u;
    __syncthreads(); sm[threadIdx.x] += y; __syncthreads();
  }
  uint32_t run = bsums[blockIdx.x] + sm[threadIdx.x] - tsum;
  #pragma unroll
  for(int k = 0; k < 8; k++){ uint32_t idx = base + k; if(idx < n) out[idx] = run; run += xs[k]; }
}

// ---- cluster ids ----
__global__ void k_cluster(const int* labels, const uint32_t* rank_, int* cluster_i, float* outC){
  int i = blockIdx.x*256 + threadIdx.x;
  if(i >= N_NODES) return;
  int c = (int)rank_[labels[i]];
  cluster_i[i] = c;
  outC[i] = (float)c;
}

// ---- wave-aggregated counting (giant component would serialize naive atomics) ----
__global__ void k_counts(const int* cluster_i, uint32_t* counts){
  int i = blockIdx.x*256 + threadIdx.x;
  int lane = threadIdx.x & 63;
  int c = (i < N_NODES) ? cluster_i[i] : -1;
  unsigned long long remaining = __ballot(i < N_NODES);
  while(remaining){
    int leader = __ffsll(remaining) - 1;
    int lc = __shfl(c, leader);
    unsigned long long grp = __ballot(c == lc) & remaining;
    if(lane == leader) atomicAdd(&counts[lc], (uint32_t)__popcll(grp));
    remaining &= ~grp;
  }
}
__global__ void k_scatter(const int* cluster_i, uint32_t* cursor, uint32_t* order){
  int i = blockIdx.x*256 + threadIdx.x;
  int lane = threadIdx.x & 63;
  int c = (i < N_NODES) ? cluster_i[i] : -1;
  unsigned long long remaining = __ballot(i < N_NODES);
  while(remaining){
    int leader = __ffsll(remaining) - 1;
    int lc = __shfl(c, leader);
    unsigned long long grp = __ballot(c == lc) & remaining;
    int b = 0;
    if(lane == leader) b = (int)atomicAdd(&cursor[lc], (uint32_t)__popcll(grp));
    b = __shfl(b, leader);
    if((grp >> lane) & 1ull){
      uint32_t sub = (uint32_t)__popcll(grp & ((1ull << lane) - 1ull));
      order[(uint32_t)b + sub] = (uint32_t)i;
    }
    remaining &= ~grp;
  }
}

// ---- segmented mean over sorted-by-cluster order ----
__global__ void k_segsum(const float* px, const uint32_t* order, const int* cluster_i, float* outP){
  int wid = (int)((blockIdx.x*blockDim.x + threadIdx.x) >> 6);
  int lane = threadIdx.x & 63;
  int start = wid * SEG_CH;
  if(start >= N_NODES) return;
  int end = start + SEG_CH; if(end > N_NODES) end = N_NODES;
  float ax = 0.f, ay = 0.f; int cur = -1;
  for(int j = start; j < end; j++){
    uint32_t i = order[j];
    int c = cluster_i[i];
    if(c != cur){
      if(cur >= 0){
        atomicAdd(&outP[(size_t)cur*FDIM + 2*lane], ax);
        atomicAdd(&outP[(size_t)cur*FDIM + 2*lane + 1], ay);
      }
      cur = c; ax = 0.f; ay = 0.f;
    }
    const float2* row = (const float2*)(px + (size_t)i*FDIM);
    float2 v = row[lane];
    ax += v.x; ay += v.y;
  }
  if(cur >= 0){
    atomicAdd(&outP[(size_t)cur*FDIM + 2*lane], ax);
    atomicAdd(&outP[(size_t)cur*FDIM + 2*lane + 1], ay);
  }
}
__global__ void k_pnorm(const uint32_t* counts, float* outP){
  int nw = (gridDim.x*blockDim.x) >> 6;
  int wid = (int)((blockIdx.x*blockDim.x + threadIdx.x) >> 6);
  int lane = threadIdx.x & 63;
  for(int r = wid; r < N_NODES; r += nw){
    uint32_t cnt = counts[r];
    if(cnt > 1){
      float fc = (float)cnt;
      float2* row = (float2*)(outP + (size_t)r*FDIM);
      float2 v = row[lane]; v.x /= fc; v.y /= fc; row[lane] = v;
    }
  }
}

// ---- edges + pair keys ----
__global__ void k_edges(const int* src, const int* dst, const int* cluster_i, uint32_t* sc,
                        float* outE, uint32_t* kc, uint32_t* vlist){
  int e = blockIdx.x*256 + threadIdx.x;
  if(e >= N_EDGES) return;
  int cu = cluster_i[src[e]];
  int cv = cluster_i[dst[e]];
  bool val = (cu != cv);
  outE[e] = val ? (float)cu : -1.0f;
  outE[N_EDGES + e] = val ? (float)cv : -1.0f;
  if(val){
    int a = cu < cv ? cu : cv, b = cu < cv ? cv : cu;
    uint32_t C = sc[SC_C];
    kc[e] = (uint32_t)a * C + (uint32_t)b;
    uint32_t p = atomicAdd(&sc[SC_VCNT], 1u);
    vlist[p] = (uint32_t)e;
  } else {
    kc[e] = 0xFFFFFFFFu;
  }
}
__global__ void k_bitmap(const uint32_t* kc, uint32_t* bitmap){
  int e = blockIdx.x*256 + threadIdx.x;
  if(e >= N_EDGES) return;
  uint32_t k = kc[e];
  if(k != 0xFFFFFFFFu) atomicOr(&bitmap[k >> 5], 1u << (k & 31u));
}
__global__ void k_dualacc(const float* dx, const uint32_t* vlist, const uint32_t* kc,
                          const uint32_t* bitmap, const uint32_t* wpref, const uint32_t* sc,
                          float* outD, uint32_t* dcnt){
  int nw = (gridDim.x*blockDim.x) >> 6;
  int wid = (int)((blockIdx.x*blockDim.x + threadIdx.x) >> 6);
  int lane = threadIdx.x & 63;
  uint32_t vc = sc[SC_VCNT];
  for(uint32_t k = (uint32_t)wid; k < vc; k += (uint32_t)nw){
    uint32_t e = vlist[k];
    uint32_t kcv = kc[e];
    uint32_t wi = kcv >> 5, bi = kcv & 31u;
    uint32_t r = wpref[wi] + __popc(bitmap[wi] & ((1u << bi) - 1u));
    const float2* row = (const float2*)(dx + (size_t)e*FDIM);
    float2 v = row[lane];
    atomicAdd(&outD[(size_t)r*FDIM + 2*lane], v.x);
    atomicAdd(&outD[(size_t)r*FDIM + 2*lane + 1], v.y);
    if(lane == 0) atomicAdd(&dcnt[r], 1u);
  }
}
__global__ void k_dualnorm(const uint32_t* dcnt, const uint32_t* sc, float* outD){
  int nw = (gridDim.x*blockDim.x) >> 6;
  int wid = (int)((blockIdx.x*blockDim.x + threadIdx.x) >> 6);
  int lane = threadIdx.x & 63;
  uint32_t U = sc[SC_U];
  for(uint32_t r = (uint32_t)wid; r < U; r += (uint32_t)nw){
    uint32_t cnt = dcnt[r];
    if(cnt > 1){
      float fc = (float)cnt;
      float2* row = (float2*)(outD + (size_t)r*FDIM);
      float2 v = row[lane]; v.x /= fc; v.y /= fc; row[lane] = v;
    }
  }
}

extern "C" void kernel_launch(void* const* d_in, const int* in_sizes, int n_in,
                              void* d_out, int out_size, void* d_ws, size_t ws_size,
                              hipStream_t stream){
  (void)in_sizes; (void)n_in; (void)out_size;
  const float* primal_x = (const float*)d_in[0];
  const float* dual_x   = (const float*)d_in[1];
  const float* att      = (const float*)d_in[2];
  const int*   pei      = (const int*)d_in[3];
  const int* src = pei;
  const int* dst = pei + N_EDGES;

  float* out  = (float*)d_out;
  float* outP = out;                                    // (N, F) means
  float* outD = out + (size_t)N_NODES*FDIM;             // (E, F) dual means
  float* outE = outD + (size_t)N_EDGES*FDIM;            // (2, E) edge index (as float)
  float* outC = outE + (size_t)2*N_EDGES;               // (N,) cluster (as float)

  uint32_t* w = (uint32_t*)d_ws;
  size_t words_avail = ws_size / 4;
  const size_t FIXED = 64 + 65536 + 65536 + (size_t)N_NODES + (size_t)N_EDGES
                     + TIECAP + 7*(size_t)N_NODES + ((size_t)N_EDGES + 3)/4
                     + 2*(size_t)N_EDGES + 4096;
  size_t wcap = (words_avail > FIXED) ? (words_avail - FIXED)/2 : 1;
  if(wcap > 8388608) wcap = 8388608;   // supports C up to 16384

  size_t o = 0;
  uint32_t* sc     = w;               o += 64;
  uint32_t* hist1  = w + o;           o += 65536;
  uint32_t* hist2  = w + o;           o += 65536;
  uint32_t* counts = w + o;           o += N_NODES;
  uint32_t* dcnt   = w + o;           o += N_EDGES;
  uint32_t* bitmap = w + o;           o += wcap;
  size_t zero_words = o;              // everything above zeroed per call
  uint32_t* tieIdx = w + o;           o += TIECAP;
  int* parent      = (int*)(w + o);   o += N_NODES;
  int* labels      = (int*)(w + o);   o += N_NODES;
  uint32_t* flags  = w + o;           o += N_NODES;
  uint32_t* rank_  = w + o;           o += N_NODES;
  uint32_t* cursor = w + o;           o += N_NODES;
  int* cluster_i   = (int*)(w + o);   o += N_NODES;
  uint32_t* order  = w + o;           o += N_NODES;
  uint8_t* mask    = (uint8_t*)(w + o); o += ((size_t)N_EDGES + 3)/4;
  uint32_t* kc     = w + o;           o += N_EDGES;
  uint32_t* vlist  = w + o;           o += N_EDGES;
  uint32_t* wpref  = w + o;           o += wcap;
  uint32_t* bsums  = w + o;           o += 4096;

  const int EB  = (N_EDGES + 255)/256;
  const int NB  = (N_NODES + 255)/256;
  const int NSB = (N_NODES + 2047)/2048;       // 98
  const int WSB = (int)((wcap + 2047)/2048);   // <= 4096

  hipMemsetAsync(out, 0, (size_t)(N_NODES + N_EDGES)*FDIM*sizeof(float), stream);
  hipMemsetAsync(w, 0, zero_words*sizeof(uint32_t), stream);

  // top-K selection
  k_hist1<<<EB,256,0,stream>>>(att, hist1);
  k_select_scan<<<1,1024,0,stream>>>(hist1, sc, 1);
  k_hist2<<<EB,256,0,stream>>>(att, hist2, sc);
  k_select_scan<<<1,1024,0,stream>>>(hist2, sc, 2);
  k_mask<<<EB,256,0,stream>>>(att, mask, sc, tieIdx);
  k_tiesel<<<1,1024,0,stream>>>(mask, sc, tieIdx);
  // connected components (min-id roots)
  k_uf_init<<<NB,256,0,stream>>>(parent);
  k_uf_union<<<EB,256,0,stream>>>(src, dst, mask, parent);
  k_flatten<<<NB,256,0,stream>>>(parent, labels, flags);
  // compact labels -> cluster ids
  k_scan_reduce<0><<<NSB,256,0,stream>>>(flags, bsums, sc, N_NODES);
  k_scan_top<<<1,1024,0,stream>>>(bsums, NSB, sc, 1);
  k_scan_apply<0><<<NSB,256,0,stream>>>(flags, bsums, rank_, sc, N_NODES);
  k_cluster<<<NB,256,0,stream>>>(labels, rank_, cluster_i, outC);
  // primal mean via counting sort + contiguous segmented reduction
  k_counts<<<NB,256,0,stream>>>(cluster_i, counts);
  k_scan_reduce<0><<<NSB,256,0,stream>>>(counts, bsums, sc, N_NODES);
  k_scan_top<<<1,1024,0,stream>>>(bsums, NSB, sc, 0);
  k_scan_apply<0><<<NSB,256,0,stream>>>(counts, bsums, cursor, sc, N_NODES);
  k_scatter<<<NB,256,0,stream>>>(cluster_i, cursor, order);
  {
    int segw = (N_NODES + SEG_CH - 1)/SEG_CH;
    int segb = (segw + 3)/4;
    k_segsum<<<segb,256,0,stream>>>(primal_x, order, cluster_i, outP);
  }
  k_pnorm<<<512,256,0,stream>>>(counts, outP);
  // edges + dual-pair ranking via bitmap popcount-prefix
  k_edges<<<EB,256,0,stream>>>(src, dst, cluster_i, sc, outE, kc, vlist);
  k_bitmap<<<EB,256,0,stream>>>(kc, bitmap);
  k_scan_reduce<1><<<WSB,256,0,stream>>>(bitmap, bsums, sc, 0);
  k_scan_top<<<1,1024,0,stream>>>(bsums, WSB, sc, 2);
  k_scan_apply<1><<<WSB,256,0,stream>>>(bitmap, bsums, wpref, sc, 0);
  k_dualacc<<<1024,256,0,stream>>>(dual_x, vlist, kc, bitmap, wpref, sc, outD, dcnt);
  k_dualnorm<<<256,256,0,stream>>>(dcnt, sc, outD);
}